// Round 3
// baseline (250.122 us; speedup 1.0000x reference)
//
#include <hip/hip_runtime.h>
#include <hip/hip_bf16.h>

// out[e] = tanh(prop[idx_i[e]] @ wi1) @ wi2 + tanh(prop[idx_j[e]] @ wj1) @ wj2
// Factored: F_I = mlp(prop, wi*), F_J = mlp(prop, wj*)  [per-node, 16x fewer FLOPs]
//           out[e] = F_I[idx_i[e]] + F_J[idx_j[e]]      [gather-add, HBM-write-bound]

typedef __attribute__((ext_vector_type(8))) short bf16x8;   // 8 bf16 (4 VGPRs)
typedef __attribute__((ext_vector_type(4))) float f32x4;    // MFMA accumulator

__device__ __forceinline__ unsigned short f2bf(float f) {
    // round-to-nearest-even fp32 -> bf16 (inputs are normal floats)
    unsigned int u = __float_as_uint(f);
    unsigned int r = (u + 0x7fffu + ((u >> 16) & 1u)) >> 16;
    return (unsigned short)r;
}

#define LDK 136  // padded LDS row stride in bf16 elems: 272 B (16B-aligned, bank-conflict-free reads)

// dst[row] (+)= tanh(src[map(row)] @ W1) @ W2, 64 rows per block, 4 waves x 16 rows.
// map(row) = idx ? idx[row] : row.
__global__ __launch_bounds__(256) void mlp_kernel(
    const float* __restrict__ src,   // [n_src][128] fp32
    const int*   __restrict__ idx,   // [n_rows] or nullptr
    const float* __restrict__ W1,    // [128][128] fp32 (k-major)
    const float* __restrict__ W2,    // [128][128] fp32
    float*       __restrict__ dst,   // [n_rows][128] fp32
    int n_rows, int accumulate)
{
    __shared__ short Wt[128][LDK];      // W^T as bf16 bits: Wt[n][k] = W[k][n]
    __shared__ short Tl[4][16][LDK];    // per-wave tanh(h) tile (A-operand for GEMM2)

    const int tid  = threadIdx.x;
    const int lane = tid & 63;
    const int wave = tid >> 6;
    const int lo   = lane & 15;   // col within 16-tile / A row
    const int q    = lane >> 4;   // k-group (A/B) / row-group (C/D)
    const int r0   = blockIdx.x * 64;

    // ---- stage W1^T into LDS (coalesced global read, ds_write_b64) ----
    {
        const int n  = tid & 127;
        const int kq = (tid >> 7) * 4;
        for (int k0 = kq; k0 < 128; k0 += 8) {
            ushort4 p;
            p.x = f2bf(W1[(k0 + 0) * 128 + n]);
            p.y = f2bf(W1[(k0 + 1) * 128 + n]);
            p.z = f2bf(W1[(k0 + 2) * 128 + n]);
            p.w = f2bf(W1[(k0 + 3) * 128 + n]);
            *reinterpret_cast<ushort4*>(&Wt[n][k0]) = p;
        }
    }
    __syncthreads();

    // ---- A fragments: 16 rows per wave, row = lane&15, k = (lane>>4)*8 + i ----
    int arow   = r0 + wave * 16 + lo;
    int arow_c = arow < n_rows ? arow : n_rows - 1;
    int srow   = idx ? idx[arow_c] : arow_c;
    const float4* ap = reinterpret_cast<const float4*>(src + (size_t)srow * 128);

    bf16x8 afr[4];
    #pragma unroll
    for (int kk = 0; kk < 4; ++kk) {
        float4 p0 = ap[kk * 8 + q * 2 + 0];
        float4 p1 = ap[kk * 8 + q * 2 + 1];
        afr[kk][0] = (short)f2bf(p0.x); afr[kk][1] = (short)f2bf(p0.y);
        afr[kk][2] = (short)f2bf(p0.z); afr[kk][3] = (short)f2bf(p0.w);
        afr[kk][4] = (short)f2bf(p1.x); afr[kk][5] = (short)f2bf(p1.y);
        afr[kk][6] = (short)f2bf(p1.z); afr[kk][7] = (short)f2bf(p1.w);
    }

    // ---- GEMM1: h = A @ W1 (B frag: col = lane&15 of n-tile, k-contiguous from Wt) ----
    f32x4 acc[8];
    #pragma unroll
    for (int nb = 0; nb < 8; ++nb) acc[nb] = f32x4{0.f, 0.f, 0.f, 0.f};
    #pragma unroll
    for (int nb = 0; nb < 8; ++nb) {
        const int col = nb * 16 + lo;
        #pragma unroll
        for (int kk = 0; kk < 4; ++kk) {
            bf16x8 b = *reinterpret_cast<const bf16x8*>(&Wt[col][kk * 32 + q * 8]);
            acc[nb] = __builtin_amdgcn_mfma_f32_16x16x32_bf16(afr[kk], b, acc[nb], 0, 0, 0);
        }
    }

    __syncthreads();  // all waves done reading W1^T before overwrite

    // ---- stage W2^T (reuse Wt) ----
    {
        const int n  = tid & 127;
        const int kq = (tid >> 7) * 4;
        for (int k0 = kq; k0 < 128; k0 += 8) {
            ushort4 p;
            p.x = f2bf(W2[(k0 + 0) * 128 + n]);
            p.y = f2bf(W2[(k0 + 1) * 128 + n]);
            p.z = f2bf(W2[(k0 + 2) * 128 + n]);
            p.w = f2bf(W2[(k0 + 3) * 128 + n]);
            *reinterpret_cast<ushort4*>(&Wt[n][k0]) = p;
        }
    }
    // ---- tanh, C/D layout (col=lane&15, row=(lane>>4)*4+r) -> Tl row-major ----
    #pragma unroll
    for (int nb = 0; nb < 8; ++nb) {
        #pragma unroll
        for (int r = 0; r < 4; ++r) {
            Tl[wave][q * 4 + r][nb * 16 + lo] = (short)f2bf(tanhf(acc[nb][r]));
        }
    }
    __syncthreads();

    // ---- A2 fragments from tanh tile (row = lane&15, k-contiguous) ----
    bf16x8 a2[4];
    #pragma unroll
    for (int kk = 0; kk < 4; ++kk)
        a2[kk] = *reinterpret_cast<const bf16x8*>(&Tl[wave][lo][kk * 32 + q * 8]);

    // ---- GEMM2: y = tanh(h) @ W2 ----
    f32x4 acc2[8];
    #pragma unroll
    for (int nb = 0; nb < 8; ++nb) acc2[nb] = f32x4{0.f, 0.f, 0.f, 0.f};
    #pragma unroll
    for (int nb = 0; nb < 8; ++nb) {
        const int col = nb * 16 + lo;
        #pragma unroll
        for (int kk = 0; kk < 4; ++kk) {
            bf16x8 b = *reinterpret_cast<const bf16x8*>(&Wt[col][kk * 32 + q * 8]);
            acc2[nb] = __builtin_amdgcn_mfma_f32_16x16x32_bf16(a2[kk], b, acc2[nb], 0, 0, 0);
        }
    }

    // ---- store (C/D layout) ----
    #pragma unroll
    for (int r = 0; r < 4; ++r) {
        int row = r0 + wave * 16 + q * 4 + r;
        if (row < n_rows) {
            float* drow = dst + (size_t)row * 128;
            #pragma unroll
            for (int nb = 0; nb < 8; ++nb) {
                int c = nb * 16 + lo;
                if (accumulate) drow[c] += acc2[nb][r];
                else            drow[c]  = acc2[nb][r];
            }
        }
    }
}

// out[e] = F_I[idx_i[e]] + F_J[idx_j[e]], float4-vectorized, grid-stride.
__global__ __launch_bounds__(256) void gather_add_kernel(
    const float4* __restrict__ FI, const float4* __restrict__ FJ,
    const int* __restrict__ idx_i, const int* __restrict__ idx_j,
    float4* __restrict__ out, int n_edges)
{
    const int total = n_edges * 32;  // 32 float4 per 128-float row
    for (int t = blockIdx.x * 256 + threadIdx.x; t < total; t += gridDim.x * 256) {
        int e  = t >> 5;
        int qq = t & 31;
        int ni = idx_i[e];
        int nj = idx_j[e];
        float4 a = FI[(size_t)ni * 32 + qq];
        float4 b = FJ[(size_t)nj * 32 + qq];
        out[t] = make_float4(a.x + b.x, a.y + b.y, a.z + b.z, a.w + b.w);
    }
}

extern "C" void kernel_launch(void* const* d_in, const int* in_sizes, int n_in,
                              void* d_out, int out_size, void* d_ws, size_t ws_size,
                              hipStream_t stream)
{
    const float* prop  = (const float*)d_in[0];
    const int*   idx_i = (const int*)d_in[1];
    const int*   idx_j = (const int*)d_in[2];
    const float* wi1   = (const float*)d_in[3];
    const float* wi2   = (const float*)d_in[4];
    const float* wj1   = (const float*)d_in[5];
    const float* wj2   = (const float*)d_in[6];
    float* out = (float*)d_out;

    const int n_nodes = in_sizes[0] / 128;
    const int n_edges = in_sizes[1];

    const size_t f_elems = (size_t)n_nodes * 128;
    const size_t need    = 2 * f_elems * sizeof(float);

    if (ws_size >= need) {
        // Fast path: per-node MLPs into workspace, then gather-add.
        float* FI = (float*)d_ws;
        float* FJ = FI + f_elems;
        int nblk = (n_nodes + 63) / 64;
        mlp_kernel<<<nblk, 256, 0, stream>>>(prop, nullptr, wi1, wi2, FI, n_nodes, 0);
        mlp_kernel<<<nblk, 256, 0, stream>>>(prop, nullptr, wj1, wj2, FJ, n_nodes, 0);

        int total  = n_edges * 32;
        int blocks = (total + 255) / 256;
        if (blocks > 2048) blocks = 2048;
        gather_add_kernel<<<blocks, 256, 0, stream>>>(
            (const float4*)FI, (const float4*)FJ, idx_i, idx_j, (float4*)out, n_edges);
    } else {
        // Fallback (workspace too small): per-edge MLP with gather, then accumulate pass.
        int nblk = (n_edges + 63) / 64;
        mlp_kernel<<<nblk, 256, 0, stream>>>(prop, idx_i, wi1, wi2, out, n_edges, 0);
        mlp_kernel<<<nblk, 256, 0, stream>>>(prop, idx_j, wj1, wj2, out, n_edges, 1);
    }
}

// Round 4
// 244.419 us; speedup vs baseline: 1.0233x; 1.0233x over previous
//
#include <hip/hip_runtime.h>
#include <hip/hip_bf16.h>

// out[e] = tanh(prop[idx_i[e]] @ wi1) @ wi2 + tanh(prop[idx_j[e]] @ wj1) @ wj2
// Factored: F_I = mlp(prop, wi*), F_J = mlp(prop, wj*)  [per-node, 16x fewer FLOPs]
//           out[e] = F_I[idx_i[e]] + F_J[idx_j[e]]      [gather-add, HBM-write-bound]
//
// R3: output stores are NON-TEMPORAL (write-once stream was evicting FI/FJ from
//     L2/L3, forcing 819 MB of gather reads to HBM); idx loads NT too; the two
//     per-node MLP dispatches are merged into one.

typedef __attribute__((ext_vector_type(8))) short bf16x8;   // 8 bf16 (4 VGPRs)
typedef __attribute__((ext_vector_type(4))) float f32x4;    // MFMA accumulator / 16B vec

__device__ __forceinline__ unsigned short f2bf(float f) {
    // round-to-nearest-even fp32 -> bf16 (inputs are normal floats)
    unsigned int u = __float_as_uint(f);
    unsigned int r = (u + 0x7fffu + ((u >> 16) & 1u)) >> 16;
    return (unsigned short)r;
}

#define LDK 136  // padded LDS row stride in bf16 elems: 272 B (16B-aligned reads)

// Core: dst[row] (+)= tanh(src[map(row)] @ W1) @ W2, 64 rows/block, 4 waves x 16 rows.
__device__ __forceinline__ void mlp_block(
    const float* __restrict__ src, const int* __restrict__ idx,
    const float* __restrict__ W1, const float* __restrict__ W2,
    float* __restrict__ dst, int n_rows, int accumulate, int bid)
{
    __shared__ short Wt[128][LDK];      // W^T as bf16 bits: Wt[n][k] = W[k][n]
    __shared__ short Tl[4][16][LDK];    // per-wave tanh(h) tile (A-operand for GEMM2)

    const int tid  = threadIdx.x;
    const int lane = tid & 63;
    const int wave = tid >> 6;
    const int lo   = lane & 15;   // col within 16-tile / A row
    const int q    = lane >> 4;   // k-group (A/B) / row-group (C/D)
    const int r0   = bid * 64;

    // ---- stage W1^T into LDS (coalesced global read, ds_write_b64) ----
    {
        const int n  = tid & 127;
        const int kq = (tid >> 7) * 4;
        for (int k0 = kq; k0 < 128; k0 += 8) {
            ushort4 p;
            p.x = f2bf(W1[(k0 + 0) * 128 + n]);
            p.y = f2bf(W1[(k0 + 1) * 128 + n]);
            p.z = f2bf(W1[(k0 + 2) * 128 + n]);
            p.w = f2bf(W1[(k0 + 3) * 128 + n]);
            *reinterpret_cast<ushort4*>(&Wt[n][k0]) = p;
        }
    }
    __syncthreads();

    // ---- A fragments: 16 rows per wave, row = lane&15, k = (lane>>4)*8 + i ----
    int arow   = r0 + wave * 16 + lo;
    int arow_c = arow < n_rows ? arow : n_rows - 1;
    int srow   = idx ? idx[arow_c] : arow_c;
    const float4* ap = reinterpret_cast<const float4*>(src + (size_t)srow * 128);

    bf16x8 afr[4];
    #pragma unroll
    for (int kk = 0; kk < 4; ++kk) {
        float4 p0 = ap[kk * 8 + q * 2 + 0];
        float4 p1 = ap[kk * 8 + q * 2 + 1];
        afr[kk][0] = (short)f2bf(p0.x); afr[kk][1] = (short)f2bf(p0.y);
        afr[kk][2] = (short)f2bf(p0.z); afr[kk][3] = (short)f2bf(p0.w);
        afr[kk][4] = (short)f2bf(p1.x); afr[kk][5] = (short)f2bf(p1.y);
        afr[kk][6] = (short)f2bf(p1.z); afr[kk][7] = (short)f2bf(p1.w);
    }

    // ---- GEMM1: h = A @ W1 ----
    f32x4 acc[8];
    #pragma unroll
    for (int nb = 0; nb < 8; ++nb) acc[nb] = f32x4{0.f, 0.f, 0.f, 0.f};
    #pragma unroll
    for (int nb = 0; nb < 8; ++nb) {
        const int col = nb * 16 + lo;
        #pragma unroll
        for (int kk = 0; kk < 4; ++kk) {
            bf16x8 b = *reinterpret_cast<const bf16x8*>(&Wt[col][kk * 32 + q * 8]);
            acc[nb] = __builtin_amdgcn_mfma_f32_16x16x32_bf16(afr[kk], b, acc[nb], 0, 0, 0);
        }
    }

    __syncthreads();  // all waves done reading W1^T before overwrite

    // ---- stage W2^T (reuse Wt) ----
    {
        const int n  = tid & 127;
        const int kq = (tid >> 7) * 4;
        for (int k0 = kq; k0 < 128; k0 += 8) {
            ushort4 p;
            p.x = f2bf(W2[(k0 + 0) * 128 + n]);
            p.y = f2bf(W2[(k0 + 1) * 128 + n]);
            p.z = f2bf(W2[(k0 + 2) * 128 + n]);
            p.w = f2bf(W2[(k0 + 3) * 128 + n]);
            *reinterpret_cast<ushort4*>(&Wt[n][k0]) = p;
        }
    }
    // ---- tanh, C/D layout (col=lane&15, row=(lane>>4)*4+r) -> Tl row-major ----
    #pragma unroll
    for (int nb = 0; nb < 8; ++nb) {
        #pragma unroll
        for (int r = 0; r < 4; ++r) {
            Tl[wave][q * 4 + r][nb * 16 + lo] = (short)f2bf(tanhf(acc[nb][r]));
        }
    }
    __syncthreads();

    // ---- A2 fragments from tanh tile (row = lane&15, k-contiguous) ----
    bf16x8 a2[4];
    #pragma unroll
    for (int kk = 0; kk < 4; ++kk)
        a2[kk] = *reinterpret_cast<const bf16x8*>(&Tl[wave][lo][kk * 32 + q * 8]);

    // ---- GEMM2: y = tanh(h) @ W2 ----
    f32x4 acc2[8];
    #pragma unroll
    for (int nb = 0; nb < 8; ++nb) acc2[nb] = f32x4{0.f, 0.f, 0.f, 0.f};
    #pragma unroll
    for (int nb = 0; nb < 8; ++nb) {
        const int col = nb * 16 + lo;
        #pragma unroll
        for (int kk = 0; kk < 4; ++kk) {
            bf16x8 b = *reinterpret_cast<const bf16x8*>(&Wt[col][kk * 32 + q * 8]);
            acc2[nb] = __builtin_amdgcn_mfma_f32_16x16x32_bf16(a2[kk], b, acc2[nb], 0, 0, 0);
        }
    }

    // ---- store (C/D layout); normal (cached) stores — gather re-reads these ----
    #pragma unroll
    for (int r = 0; r < 4; ++r) {
        int row = r0 + wave * 16 + q * 4 + r;
        if (row < n_rows) {
            float* drow = dst + (size_t)row * 128;
            #pragma unroll
            for (int nb = 0; nb < 8; ++nb) {
                int c = nb * 16 + lo;
                if (accumulate) drow[c] += acc2[nb][r];
                else            drow[c]  = acc2[nb][r];
            }
        }
    }
}

// Merged per-node MLPs: blocks [0,nblk) -> FI with (w11,w12); [nblk,2*nblk) -> FJ.
__global__ __launch_bounds__(256) void mlp2_kernel(
    const float* __restrict__ src,
    const float* __restrict__ w11, const float* __restrict__ w12,
    const float* __restrict__ w21, const float* __restrict__ w22,
    float* __restrict__ FI, float* __restrict__ FJ,
    int n_rows, int nblk)
{
    const bool second = (int)blockIdx.x >= nblk;
    mlp_block(src, nullptr,
              second ? w21 : w11, second ? w22 : w12,
              second ? FJ : FI, n_rows, 0,
              second ? (int)blockIdx.x - nblk : (int)blockIdx.x);
}

// Fallback per-edge MLP (workspace too small).
__global__ __launch_bounds__(256) void mlp_kernel(
    const float* __restrict__ src, const int* __restrict__ idx,
    const float* __restrict__ W1, const float* __restrict__ W2,
    float* __restrict__ dst, int n_rows, int accumulate)
{
    mlp_block(src, idx, W1, W2, dst, n_rows, accumulate, (int)blockIdx.x);
}

// out[e] = F_I[idx_i[e]] + F_J[idx_j[e]], float4-vectorized, grid-stride.
// Output is a write-once stream -> non-temporal stores keep FI/FJ resident in L2/L3.
__global__ __launch_bounds__(256) void gather_add_kernel(
    const f32x4* __restrict__ FI, const f32x4* __restrict__ FJ,
    const int* __restrict__ idx_i, const int* __restrict__ idx_j,
    f32x4* __restrict__ out, int n_edges)
{
    const int total = n_edges * 32;  // 32 float4 per 128-float row
    for (int t = blockIdx.x * 256 + threadIdx.x; t < total; t += gridDim.x * 256) {
        int e  = t >> 5;
        int qq = t & 31;
        int ni = __builtin_nontemporal_load(&idx_i[e]);   // one-shot stream
        int nj = __builtin_nontemporal_load(&idx_j[e]);
        f32x4 a = FI[(size_t)ni * 32 + qq];               // keep cached (hot tables)
        f32x4 b = FJ[(size_t)nj * 32 + qq];
        __builtin_nontemporal_store(a + b, &out[t]);      // write-once stream
    }
}

extern "C" void kernel_launch(void* const* d_in, const int* in_sizes, int n_in,
                              void* d_out, int out_size, void* d_ws, size_t ws_size,
                              hipStream_t stream)
{
    const float* prop  = (const float*)d_in[0];
    const int*   idx_i = (const int*)d_in[1];
    const int*   idx_j = (const int*)d_in[2];
    const float* wi1   = (const float*)d_in[3];
    const float* wi2   = (const float*)d_in[4];
    const float* wj1   = (const float*)d_in[5];
    const float* wj2   = (const float*)d_in[6];
    float* out = (float*)d_out;

    const int n_nodes = in_sizes[0] / 128;
    const int n_edges = in_sizes[1];

    const size_t f_elems = (size_t)n_nodes * 128;
    const size_t need    = 2 * f_elems * sizeof(float);

    if (ws_size >= need) {
        // Fast path: per-node MLPs into workspace (one merged dispatch), then gather-add.
        float* FI = (float*)d_ws;
        float* FJ = FI + f_elems;
        int nblk = (n_nodes + 63) / 64;
        mlp2_kernel<<<2 * nblk, 256, 0, stream>>>(prop, wi1, wi2, wj1, wj2,
                                                  FI, FJ, n_nodes, nblk);

        int total  = n_edges * 32;
        int blocks = (total + 255) / 256;
        if (blocks > 2048) blocks = 2048;
        gather_add_kernel<<<blocks, 256, 0, stream>>>(
            (const f32x4*)FI, (const f32x4*)FJ, idx_i, idx_j, (f32x4*)out, n_edges);
    } else {
        // Fallback (workspace too small): per-edge MLP with gather, then accumulate pass.
        int nblk = (n_edges + 63) / 64;
        mlp_kernel<<<nblk, 256, 0, stream>>>(prop, idx_i, wi1, wi2, out, n_edges, 0);
        mlp_kernel<<<nblk, 256, 0, stream>>>(prop, idx_j, wj1, wj2, out, n_edges, 1);
    }
}

// Round 5
// 202.132 us; speedup vs baseline: 1.2374x; 1.2092x over previous
//
#include <hip/hip_runtime.h>
#include <hip/hip_bf16.h>

// out[e] = tanh(prop[idx_i[e]] @ wi1) @ wi2 + tanh(prop[idx_j[e]] @ wj1) @ wj2
// Factored: F_I = mlp(prop, wi*), F_J = mlp(prop, wj*)  [per-node, 16x fewer FLOPs]
//           out[e] = F_I[idx_i[e]] + F_J[idx_j[e]]      [gather-add]
//
// R4: F tables stored as BF16 (halves gather read traffic 819->410 MB and fits
//     25.6 MB — better L3 survival under the 410 MB output write stream).
//     NT stores on output kept. Error budget: +~0.006 absmax, still <<0.0434.

typedef __attribute__((ext_vector_type(8))) short bf16x8;   // 8 bf16 (4 VGPRs)
typedef __attribute__((ext_vector_type(4))) float f32x4;    // MFMA accumulator / 16B vec

__device__ __forceinline__ unsigned short f2bf(float f) {
    // round-to-nearest-even fp32 -> bf16 (inputs are normal floats)
    unsigned int u = __float_as_uint(f);
    unsigned int r = (u + 0x7fffu + ((u >> 16) & 1u)) >> 16;
    return (unsigned short)r;
}
__device__ __forceinline__ float bf2f(short b) {
    return __uint_as_float((unsigned int)(unsigned short)b << 16);
}

#define LDK 136  // padded LDS row stride in bf16 elems: 272 B (16B-aligned reads)

// Core: dst (+)= tanh(src[map(row)] @ W1) @ W2, 64 rows/block, 4 waves x 16 rows.
// BF16OUT: write bf16 table (no accumulate). else fp32 with optional accumulate.
template <bool BF16OUT>
__device__ __forceinline__ void mlp_block(
    const float* __restrict__ src, const int* __restrict__ idx,
    const float* __restrict__ W1, const float* __restrict__ W2,
    float* __restrict__ dstf, unsigned short* __restrict__ dstb,
    int n_rows, int accumulate, int bid)
{
    __shared__ short Wt[128][LDK];      // W^T as bf16 bits: Wt[n][k] = W[k][n]
    __shared__ short Tl[4][16][LDK];    // per-wave tanh(h) tile (A-operand for GEMM2)

    const int tid  = threadIdx.x;
    const int lane = tid & 63;
    const int wave = tid >> 6;
    const int lo   = lane & 15;   // col within 16-tile / A row
    const int q    = lane >> 4;   // k-group (A/B) / row-group (C/D)
    const int r0   = bid * 64;

    // ---- stage W1^T into LDS (coalesced global read, ds_write_b64) ----
    {
        const int n  = tid & 127;
        const int kq = (tid >> 7) * 4;
        for (int k0 = kq; k0 < 128; k0 += 8) {
            ushort4 p;
            p.x = f2bf(W1[(k0 + 0) * 128 + n]);
            p.y = f2bf(W1[(k0 + 1) * 128 + n]);
            p.z = f2bf(W1[(k0 + 2) * 128 + n]);
            p.w = f2bf(W1[(k0 + 3) * 128 + n]);
            *reinterpret_cast<ushort4*>(&Wt[n][k0]) = p;
        }
    }
    __syncthreads();

    // ---- A fragments: 16 rows per wave, row = lane&15, k = (lane>>4)*8 + i ----
    int arow   = r0 + wave * 16 + lo;
    int arow_c = arow < n_rows ? arow : n_rows - 1;
    int srow   = idx ? idx[arow_c] : arow_c;
    const float4* ap = reinterpret_cast<const float4*>(src + (size_t)srow * 128);

    bf16x8 afr[4];
    #pragma unroll
    for (int kk = 0; kk < 4; ++kk) {
        float4 p0 = ap[kk * 8 + q * 2 + 0];
        float4 p1 = ap[kk * 8 + q * 2 + 1];
        afr[kk][0] = (short)f2bf(p0.x); afr[kk][1] = (short)f2bf(p0.y);
        afr[kk][2] = (short)f2bf(p0.z); afr[kk][3] = (short)f2bf(p0.w);
        afr[kk][4] = (short)f2bf(p1.x); afr[kk][5] = (short)f2bf(p1.y);
        afr[kk][6] = (short)f2bf(p1.z); afr[kk][7] = (short)f2bf(p1.w);
    }

    // ---- GEMM1: h = A @ W1 ----
    f32x4 acc[8];
    #pragma unroll
    for (int nb = 0; nb < 8; ++nb) acc[nb] = f32x4{0.f, 0.f, 0.f, 0.f};
    #pragma unroll
    for (int nb = 0; nb < 8; ++nb) {
        const int col = nb * 16 + lo;
        #pragma unroll
        for (int kk = 0; kk < 4; ++kk) {
            bf16x8 b = *reinterpret_cast<const bf16x8*>(&Wt[col][kk * 32 + q * 8]);
            acc[nb] = __builtin_amdgcn_mfma_f32_16x16x32_bf16(afr[kk], b, acc[nb], 0, 0, 0);
        }
    }

    __syncthreads();  // all waves done reading W1^T before overwrite

    // ---- stage W2^T (reuse Wt) ----
    {
        const int n  = tid & 127;
        const int kq = (tid >> 7) * 4;
        for (int k0 = kq; k0 < 128; k0 += 8) {
            ushort4 p;
            p.x = f2bf(W2[(k0 + 0) * 128 + n]);
            p.y = f2bf(W2[(k0 + 1) * 128 + n]);
            p.z = f2bf(W2[(k0 + 2) * 128 + n]);
            p.w = f2bf(W2[(k0 + 3) * 128 + n]);
            *reinterpret_cast<ushort4*>(&Wt[n][k0]) = p;
        }
    }
    // ---- tanh, C/D layout (col=lane&15, row=(lane>>4)*4+r) -> Tl row-major ----
    #pragma unroll
    for (int nb = 0; nb < 8; ++nb) {
        #pragma unroll
        for (int r = 0; r < 4; ++r) {
            Tl[wave][q * 4 + r][nb * 16 + lo] = (short)f2bf(tanhf(acc[nb][r]));
        }
    }
    __syncthreads();

    // ---- A2 fragments from tanh tile (row = lane&15, k-contiguous) ----
    bf16x8 a2[4];
    #pragma unroll
    for (int kk = 0; kk < 4; ++kk)
        a2[kk] = *reinterpret_cast<const bf16x8*>(&Tl[wave][lo][kk * 32 + q * 8]);

    // ---- GEMM2: y = tanh(h) @ W2 ----
    f32x4 acc2[8];
    #pragma unroll
    for (int nb = 0; nb < 8; ++nb) acc2[nb] = f32x4{0.f, 0.f, 0.f, 0.f};
    #pragma unroll
    for (int nb = 0; nb < 8; ++nb) {
        const int col = nb * 16 + lo;
        #pragma unroll
        for (int kk = 0; kk < 4; ++kk) {
            bf16x8 b = *reinterpret_cast<const bf16x8*>(&Wt[col][kk * 32 + q * 8]);
            acc2[nb] = __builtin_amdgcn_mfma_f32_16x16x32_bf16(a2[kk], b, acc2[nb], 0, 0, 0);
        }
    }

    // ---- store (C/D layout: col=nb*16+lo, row=r0+wave*16+q*4+r) ----
    #pragma unroll
    for (int r = 0; r < 4; ++r) {
        int row = r0 + wave * 16 + q * 4 + r;
        if (row < n_rows) {
            #pragma unroll
            for (int nb = 0; nb < 8; ++nb) {
                int c = nb * 16 + lo;
                if (BF16OUT) {
                    dstb[(size_t)row * 128 + c] = f2bf(acc2[nb][r]);
                } else {
                    float* drow = dstf + (size_t)row * 128;
                    if (accumulate) drow[c] += acc2[nb][r];
                    else            drow[c]  = acc2[nb][r];
                }
            }
        }
    }
}

// Merged per-node MLPs -> bf16 tables: blocks [0,nblk) -> FI; [nblk,2*nblk) -> FJ.
__global__ __launch_bounds__(256) void mlp2_kernel(
    const float* __restrict__ src,
    const float* __restrict__ w11, const float* __restrict__ w12,
    const float* __restrict__ w21, const float* __restrict__ w22,
    unsigned short* __restrict__ FI, unsigned short* __restrict__ FJ,
    int n_rows, int nblk)
{
    const bool second = (int)blockIdx.x >= nblk;
    mlp_block<true>(src, nullptr,
                    second ? w21 : w11, second ? w22 : w12,
                    nullptr, second ? FJ : FI, n_rows, 0,
                    second ? (int)blockIdx.x - nblk : (int)blockIdx.x);
}

// Fallback per-edge MLP (workspace too small), fp32 accumulate into out.
__global__ __launch_bounds__(256) void mlp_kernel(
    const float* __restrict__ src, const int* __restrict__ idx,
    const float* __restrict__ W1, const float* __restrict__ W2,
    float* __restrict__ dst, int n_rows, int accumulate)
{
    mlp_block<false>(src, idx, W1, W2, dst, nullptr, n_rows, accumulate,
                     (int)blockIdx.x);
}

// out[e] = FI[idx_i[e]] + FJ[idx_j[e]] with bf16 tables.
// 16 lanes per edge; each lane: 2x 16B bf16x8 load, convert+add, 32B fp32 NT store.
__global__ __launch_bounds__(256) void gather_add_kernel(
    const bf16x8* __restrict__ FI, const bf16x8* __restrict__ FJ,
    const int* __restrict__ idx_i, const int* __restrict__ idx_j,
    f32x4* __restrict__ out, int n_edges)
{
    const int total = n_edges * 16;  // 16 bf16x8 chunks per 128-elem row
    for (int t = blockIdx.x * 256 + threadIdx.x; t < total; t += gridDim.x * 256) {
        int e  = t >> 4;
        int qq = t & 15;
        int ni = idx_i[e];
        int nj = idx_j[e];
        bf16x8 a = FI[(size_t)ni * 16 + qq];   // tables stay cached (hot, 25.6 MB)
        bf16x8 b = FJ[(size_t)nj * 16 + qq];
        f32x4 lo, hi;
        #pragma unroll
        for (int k = 0; k < 4; ++k) {
            lo[k] = bf2f(a[k])     + bf2f(b[k]);
            hi[k] = bf2f(a[k + 4]) + bf2f(b[k + 4]);
        }
        __builtin_nontemporal_store(lo, &out[(size_t)t * 2 + 0]);  // write-once stream
        __builtin_nontemporal_store(hi, &out[(size_t)t * 2 + 1]);
    }
}

extern "C" void kernel_launch(void* const* d_in, const int* in_sizes, int n_in,
                              void* d_out, int out_size, void* d_ws, size_t ws_size,
                              hipStream_t stream)
{
    const float* prop  = (const float*)d_in[0];
    const int*   idx_i = (const int*)d_in[1];
    const int*   idx_j = (const int*)d_in[2];
    const float* wi1   = (const float*)d_in[3];
    const float* wi2   = (const float*)d_in[4];
    const float* wj1   = (const float*)d_in[5];
    const float* wj2   = (const float*)d_in[6];
    float* out = (float*)d_out;

    const int n_nodes = in_sizes[0] / 128;
    const int n_edges = in_sizes[1];

    const size_t f_elems = (size_t)n_nodes * 128;
    const size_t need    = 2 * f_elems * sizeof(unsigned short);

    if (ws_size >= need) {
        // Fast path: per-node MLPs into bf16 tables (one dispatch), then gather-add.
        unsigned short* FI = (unsigned short*)d_ws;
        unsigned short* FJ = FI + f_elems;
        int nblk = (n_nodes + 63) / 64;
        mlp2_kernel<<<2 * nblk, 256, 0, stream>>>(prop, wi1, wi2, wj1, wj2,
                                                  FI, FJ, n_nodes, nblk);

        int total  = n_edges * 16;
        int blocks = (total + 255) / 256;
        if (blocks > 2048) blocks = 2048;
        gather_add_kernel<<<blocks, 256, 0, stream>>>(
            (const bf16x8*)FI, (const bf16x8*)FJ, idx_i, idx_j,
            (f32x4*)out, n_edges);
    } else {
        // Fallback (workspace too small): per-edge MLP with gather, then accumulate pass.
        int nblk = (n_edges + 63) / 64;
        mlp_kernel<<<nblk, 256, 0, stream>>>(prop, idx_i, wi1, wi2, out, n_edges, 0);
        mlp_kernel<<<nblk, 256, 0, stream>>>(prop, idx_j, wj1, wj2, out, n_edges, 1);
    }
}